// Round 3
// baseline (261.948 us; speedup 1.0000x reference)
//
#include <hip/hip_runtime.h>
#include <math.h>

// Problem constants (from setup_inputs): N=262144, D=128, C=1024.
// R0 sorted-gather pipeline; class_sum rewritten with branchless unroll-4
// (4 rows in flight per 16-lane group) to break latency-boundedness.
#define NUM_CLASSES 1024
#define HIST_CHUNK 2048            // samples per hist/scatter block
#define NB 128                     // number of hist/scatter blocks (N/HIST_CHUNK)

__device__ __forceinline__ int detect_mode32(const int* __restrict__ l) {
    // uniform scalar loads; 1 -> labels are int32, 0 -> int64 (read low words)
    return (l[1] | l[3] | l[5] | l[7] | l[9] | l[11] | l[13] | l[15]) != 0;
}

__device__ __forceinline__ int get_label(const int* __restrict__ l, int i, int mode32) {
    return l[mode32 ? i : (i << 1)] & (NUM_CLASSES - 1);
}

// ---------------- Kernel 1: per-block partial histograms (transposed out) ----------------
__global__ void hist_kernel(const int* __restrict__ labels, int n,
                            int* __restrict__ pT) {        // [C][NB]
    __shared__ int h[NUM_CLASSES];
    const int mode32 = detect_mode32(labels);
    for (int i = threadIdx.x; i < NUM_CLASSES; i += blockDim.x) h[i] = 0;
    __syncthreads();
    const int base = blockIdx.x * HIST_CHUNK;
    for (int k = threadIdx.x; k < HIST_CHUNK; k += blockDim.x) {
        int i = base + k;
        if (i < n) atomicAdd(&h[get_label(labels, i, mode32)], 1);
    }
    __syncthreads();
    for (int c = threadIdx.x; c < NUM_CLASSES; c += blockDim.x)
        pT[c * NB + blockIdx.x] = h[c];
}

// ---------------- Kernel 2a: per-class prefix along blocks (wave per class) ----------------
__global__ __launch_bounds__(512) void scanA_kernel(int* __restrict__ pT,
                                                    int* __restrict__ totals) {
    const int wave = threadIdx.x >> 6;
    const int lane = threadIdx.x & 63;
    const int c = blockIdx.x * 8 + wave;        // 128 blocks x 8 waves = 1024
    int* p = pT + c * NB;
    const int v0 = p[2 * lane];
    const int v1 = p[2 * lane + 1];
    int s = v0 + v1;
    #pragma unroll
    for (int d = 1; d < 64; d <<= 1) {
        int t = __shfl_up(s, d, 64);
        if (lane >= d) s += t;
    }
    const int base = s - v0 - v1;               // exclusive prefix before this pair
    p[2 * lane]     = base;
    p[2 * lane + 1] = base + v0;
    if (lane == 63) totals[c] = s;
}

// ---------------- Kernel 2b: cross-class exclusive scan (1 block) ----------------
__global__ void scanB_kernel(const int* __restrict__ totals,
                             int* __restrict__ offsets,
                             int* __restrict__ counts,
                             float* __restrict__ accum,
                             int* __restrict__ ticket) {
    __shared__ int tmp[NUM_CLASSES];
    const int c = threadIdx.x;                  // blockDim.x == 1024
    const int v = totals[c];
    tmp[c] = v;
    __syncthreads();
    for (int off = 1; off < NUM_CLASSES; off <<= 1) {
        int add = (c >= off) ? tmp[c - off] : 0;
        __syncthreads();
        tmp[c] += add;
        __syncthreads();
    }
    offsets[c] = tmp[c] - v;
    counts[c]  = v;
    if (c == 0) { accum[0] = 0.0f; accum[1] = 0.0f; *ticket = 0; }
}

// ---------------- Kernel 3: scatter via LDS cursors (no global atomics) ----------------
__global__ void scatter_kernel(const int* __restrict__ labels, int n,
                               const int* __restrict__ pT,
                               const int* __restrict__ offsets,
                               int* __restrict__ sorted) {
    __shared__ int cur[NUM_CLASSES];
    const int mode32 = detect_mode32(labels);
    for (int c = threadIdx.x; c < NUM_CLASSES; c += blockDim.x)
        cur[c] = offsets[c] + pT[c * NB + blockIdx.x];
    __syncthreads();
    const int base = blockIdx.x * HIST_CHUNK;
    for (int k = threadIdx.x; k < HIST_CHUNK; k += blockDim.x) {
        int i = base + k;
        if (i < n) {
            int pos = atomicAdd(&cur[get_label(labels, i, mode32)], 1);  // LDS atomic
            sorted[pos] = i;
        }
    }
}

// ---------------- Kernel 4: per-class normalized sum + loss (+finalize) ----------------
// One block (8 waves) per class. 16 lanes per row; group handles rows
// r0, r0+32, r0+64, ... Main loop unrolled x4, branchless: 4 rows' loads
// (8x dwordx4) issued back-to-back, then 4 independent shfl-reduce chains.
// FULL = count>>5 iterations are valid for ALL 32 groups (uniform trip count),
// then one masked tail. Accumulation order per group identical to prior
// versions (bitwise-identical result).
#define WPB 8

__device__ __forceinline__ float dot8(const float4 a, const float4 b) {
    return a.x*a.x + a.y*a.y + a.z*a.z + a.w*a.w
         + b.x*b.x + b.y*b.y + b.z*b.z + b.w*b.w;
}

__device__ __forceinline__ float red16(float sq) {
    sq += __shfl_xor(sq, 1, 64);
    sq += __shfl_xor(sq, 2, 64);
    sq += __shfl_xor(sq, 4, 64);
    sq += __shfl_xor(sq, 8, 64);
    return sq;
}

__global__ __launch_bounds__(512, 4) void class_sum_kernel(
        const float* __restrict__ emb,      // N x 128 fp32
        const int* __restrict__ sorted,
        const int* __restrict__ offsets,
        const int* __restrict__ counts,
        float* __restrict__ accum,          // [0]=loss_sum, [1]=n_valid
        int* __restrict__ ticket,
        float* __restrict__ out) {
    const int c     = blockIdx.x;
    const int start = offsets[c];
    const int count = counts[c];
    const int wave  = threadIdx.x >> 6;
    const int lane  = threadIdx.x & 63;
    const int g     = lane >> 4;            // row-group 0..3 within wave
    const int sub   = lane & 15;            // lane within row
    const int r0    = wave * 4 + g;         // 0..31

    const float4* emb4 = (const float4*)emb;
    const int* sp = sorted + start;

    float4 aLo = make_float4(0.f, 0.f, 0.f, 0.f);
    float4 aHi = make_float4(0.f, 0.f, 0.f, 0.f);

    // t < FULL  =>  r0 + 32*t < count for every r0 in [0,32)
    const int FULL = count >> 5;
    int t = 0;
    for (; t + 4 <= FULL; t += 4) {
        const int i0 = sp[r0 + 32 * t];
        const int i1 = sp[r0 + 32 * (t + 1)];
        const int i2 = sp[r0 + 32 * (t + 2)];
        const int i3 = sp[r0 + 32 * (t + 3)];
        const float4* p0 = emb4 + (size_t)i0 * 32;
        const float4* p1 = emb4 + (size_t)i1 * 32;
        const float4* p2 = emb4 + (size_t)i2 * 32;
        const float4* p3 = emb4 + (size_t)i3 * 32;
        // issue all 8 row loads before any consumer
        float4 a0 = p0[sub], a1 = p0[sub + 16];
        float4 b0 = p1[sub], b1 = p1[sub + 16];
        float4 c0 = p2[sub], c1 = p2[sub + 16];
        float4 d0 = p3[sub], d1 = p3[sub + 16];
        // 4 independent reduce chains (ILP over shfl latency)
        float sa = red16(dot8(a0, a1));
        float sb = red16(dot8(b0, b1));
        float sc = red16(dot8(c0, c1));
        float sd = red16(dot8(d0, d1));
        float ia = 1.0f / fmaxf(sqrtf(sa), 1e-12f);
        float ib = 1.0f / fmaxf(sqrtf(sb), 1e-12f);
        float ic = 1.0f / fmaxf(sqrtf(sc), 1e-12f);
        float id = 1.0f / fmaxf(sqrtf(sd), 1e-12f);
        // sequential adds preserve accumulation order (t ascending)
        aLo.x += a0.x * ia; aLo.y += a0.y * ia; aLo.z += a0.z * ia; aLo.w += a0.w * ia;
        aHi.x += a1.x * ia; aHi.y += a1.y * ia; aHi.z += a1.z * ia; aHi.w += a1.w * ia;
        aLo.x += b0.x * ib; aLo.y += b0.y * ib; aLo.z += b0.z * ib; aLo.w += b0.w * ib;
        aHi.x += b1.x * ib; aHi.y += b1.y * ib; aHi.z += b1.z * ib; aHi.w += b1.w * ib;
        aLo.x += c0.x * ic; aLo.y += c0.y * ic; aLo.z += c0.z * ic; aLo.w += c0.w * ic;
        aHi.x += c1.x * ic; aHi.y += c1.y * ic; aHi.z += c1.z * ic; aHi.w += c1.w * ic;
        aLo.x += d0.x * id; aLo.y += d0.y * id; aLo.z += d0.z * id; aLo.w += d0.w * id;
        aHi.x += d1.x * id; aHi.y += d1.y * id; aHi.z += d1.z * id; aHi.w += d1.w * id;
    }
    for (; t < FULL; ++t) {
        const int i0 = sp[r0 + 32 * t];
        const float4* p0 = emb4 + (size_t)i0 * 32;
        float4 a0 = p0[sub], a1 = p0[sub + 16];
        float ia = 1.0f / fmaxf(sqrtf(red16(dot8(a0, a1))), 1e-12f);
        aLo.x += a0.x * ia; aLo.y += a0.y * ia; aLo.z += a0.z * ia; aLo.w += a0.w * ia;
        aHi.x += a1.x * ia; aHi.y += a1.y * ia; aHi.z += a1.z * ia; aHi.w += a1.w * ia;
    }
    {   // masked tail: row r = r0 + 32*FULL; group-uniform validity
        const int r = r0 + 32 * FULL;
        if (r < count) {
            const int i0 = sp[r];
            const float4* p0 = emb4 + (size_t)i0 * 32;
            float4 a0 = p0[sub], a1 = p0[sub + 16];
            float ia = 1.0f / fmaxf(sqrtf(red16(dot8(a0, a1))), 1e-12f);
            aLo.x += a0.x * ia; aLo.y += a0.y * ia; aLo.z += a0.z * ia; aLo.w += a0.w * ia;
            aHi.x += a1.x * ia; aHi.y += a1.y * ia; aHi.z += a1.z * ia; aHi.w += a1.w * ia;
        }
    }

    // Reduce 32 partial vectors (8 waves x 4 groups) of 128 dims.
    __shared__ float s[WPB * 4][16][8];     // 16 KB
    {
        float* dst = s[wave * 4 + g][sub];
        dst[0] = aLo.x; dst[1] = aLo.y; dst[2] = aLo.z; dst[3] = aLo.w;
        dst[4] = aHi.x; dst[5] = aHi.y; dst[6] = aHi.z; dst[7] = aHi.w;
    }
    __syncthreads();

    __shared__ float red[128];
    if (threadIdx.x < 128) {
        const int d  = threadIdx.x;
        const int dd = d & 63;
        const int sb = dd >> 2;
        const int j  = (d >> 6) * 4 + (dd & 3);
        float tt = 0.0f;
        #pragma unroll
        for (int k = 0; k < WPB * 4; k++) tt += s[k][sb][j];
        red[d] = tt * tt;
    }
    __syncthreads();
    if (threadIdx.x < 64) {
        float x = red[threadIdx.x] + red[threadIdx.x + 64];
        #pragma unroll
        for (int off = 32; off; off >>= 1) x += __shfl_xor(x, off, 64);
        if (threadIdx.x == 0) {
            if (count >= 2) {
                float nrm = sqrtf(x);                   // = sum over class of sim
                float per_class = ((float)count - nrm) / (float)count;
                atomicAdd(&accum[0], per_class);
                atomicAdd(&accum[1], 1.0f);
            }
            __threadfence();
            int old = atomicAdd(ticket, 1);
            if (old == NUM_CLASSES - 1) {
                // device-scope atomic reads (cross-XCD safe)
                float ls = atomicAdd(&accum[0], 0.0f);
                float nv = atomicAdd(&accum[1], 0.0f);
                out[0] = (nv > 0.0f) ? (ls / nv) : 0.0f;
            }
        }
    }
}

extern "C" void kernel_launch(void* const* d_in, const int* in_sizes, int n_in,
                              void* d_out, int out_size, void* d_ws, size_t ws_size,
                              hipStream_t stream) {
    const float* emb  = (const float*)d_in[0];   // fp32, N x 128
    const int* labels = (const int*)d_in[1];     // int32 (int64 handled inline)
    const int n = in_sizes[1];                   // 262144 samples

    // Workspace layout (~1.55 MB)
    char* ws = (char*)d_ws;
    int*   counts  = (int*)(ws + 0);                       // 1024 ints
    int*   offsets = (int*)(ws + 4096);                    // 1024 ints
    int*   totals  = (int*)(ws + 8192);                    // 1024 ints
    float* accum   = (float*)(ws + 12288);                 // 2 floats
    int*   ticket  = (int*)(ws + 12304);                   // 1 int
    int*   sorted  = (int*)(ws + 16384);                   // n ints (1 MB)
    int*   pT      = (int*)(ws + 16384 + (size_t)n * 4);   // C*NB ints (512 KB)

    hist_kernel <<<NB, 256, 0, stream>>>(labels, n, pT);
    scanA_kernel<<<NB, 512, 0, stream>>>(pT, totals);
    scanB_kernel<<<1, NUM_CLASSES, 0, stream>>>(totals, offsets, counts, accum, ticket);
    scatter_kernel<<<NB, 256, 0, stream>>>(labels, n, pT, offsets, sorted);
    class_sum_kernel<<<NUM_CLASSES, 512, 0, stream>>>(emb, sorted, offsets, counts,
                                                      accum, ticket, (float*)d_out);
}